// Round 4
// baseline (99.753 us; speedup 1.0000x reference)
//
#include <hip/hip_runtime.h>
#include <math.h>

// Problem constants: B=8, C=16, N=65536, K_CAND=10, K_TOP=4
#define BB 8
#define CC 16
#define NN 65536
#define KC 10
#define KT 4

#define TPTS 64            // points per tile
#define BLK  256           // threads per block (4 lanes per point)
#define ITERS 8            // tiles per block -> 8192/8 = 1024 blocks = 4/CU resident

typedef __attribute__((address_space(3))) void lds_t;
typedef __attribute__((address_space(1))) void glob_t;

// Software-pipelined: per iteration, ds_read current tile -> barrier ->
// issue global_load_lds for next tile (flies under the compute) -> compute ->
// vmcnt(0)+barrier. Raw asm barriers avoid __syncthreads' full vmcnt drain.
__global__ __launch_bounds__(BLK, 4) void swg_kernel(
    const float* __restrict__ orig,   // [B][C][N]
    const float* __restrict__ samp,   // [B][C][N][KC]
    const float* __restrict__ w1,     // [2C]
    const float* __restrict__ w2,     // [2C]
    const float* __restrict__ b2p,    // scalar
    float* __restrict__ out)          // [B][C][N]
{
    __shared__ float4 buf[CC * TPTS * KC / 4];   // 2560 float4 = 40 KB

    const int t   = threadIdx.x;
    const int bid = blockIdx.x;
    const int l   = t & 63;
    const int wid = t >> 6;

    // Per-lane gather offsets for staging (float4 units within batch b).
    // Buffer float4 idx i holds channel c=i/160, slab-float4 r=i%160.
    int goff[10];
#pragma unroll
    for (int j = 0; j < 10; ++j) {
        const int idx = wid * 640 + j * 64 + l;
        const int c   = idx / 160;
        const int r   = idx - c * 160;
        goff[j] = c * (NN * KC / 4) + r;          // c*163840 + r
    }
    char* lds_base = (char*)buf + wid * 10240;    // wave-uniform LDS base

    const int T0 = bid * ITERS;                   // first tile (8 | 1024 -> same b)
    const int b  = T0 >> 10;
    const float4* sampB = (const float4*)samp + (size_t)b * (CC * (size_t)NN * KC / 4);

    const int q = t & 3;                          // channel group 0..3
    const int p = t >> 2;                         // local point 0..63

    const float b2 = b2p[0];
    float ws1[4], wo2[4], ws2[4];
#pragma unroll
    for (int cc = 0; cc < 4; ++cc) {
        const int c = q * 4 + cc;
        ws1[cc] = w1[CC + c];
        wo2[cc] = w2[c];
        ws2[cc] = w2[CC + c];
    }

    // ---- prologue: stage tile 0 + orig(0) ----
    {
        const int n0q = (T0 & 1023) * 160;        // n0*10/4
#pragma unroll
        for (int j = 0; j < 10; ++j)
            __builtin_amdgcn_global_load_lds(
                (const glob_t*)(sampB + n0q + goff[j]),
                (lds_t*)(lds_base + j * 1024), 16, 0, 0);
    }
    float o[4];
    {
        const int n = (T0 & 1023) * 64 + p;
#pragma unroll
        for (int cc = 0; cc < 4; ++cc)
            o[cc] = orig[((size_t)(b * CC + q * 4 + cc)) * NN + n];
    }
    asm volatile("s_waitcnt vmcnt(0)\ns_barrier" ::: "memory");

    for (int g = 0; g < ITERS; ++g) {
        const int T = T0 + g;
        const int n = (T & 1023) * 64 + p;

        // ---- copy this lane's 4 channels from LDS to registers ----
        float v[4][KC];
#pragma unroll
        for (int cc = 0; cc < 4; ++cc) {
            const int c = q * 4 + cc;
            const float2* lp = (const float2*)((const float*)buf + c * (TPTS * KC) + p * KC);
#pragma unroll
            for (int j = 0; j < 5; ++j) {
                const float2 x = lp[j];
                v[cc][2 * j]     = x.x;
                v[cc][2 * j + 1] = x.y;
            }
        }
        // all reads complete before anyone overwrites the buffer
        asm volatile("s_waitcnt lgkmcnt(0)\ns_barrier" ::: "memory");

        // ---- prefetch next tile (overlaps with compute below) ----
        float o_nx[4];
        if (g + 1 < ITERS) {
            const int Tn  = T + 1;
            const int n0q = (Tn & 1023) * 160;
#pragma unroll
            for (int j = 0; j < 10; ++j)
                __builtin_amdgcn_global_load_lds(
                    (const glob_t*)(sampB + n0q + goff[j]),
                    (lds_t*)(lds_base + j * 1024), 16, 0, 0);
            const int nn = (Tn & 1023) * 64 + p;
#pragma unroll
            for (int cc = 0; cc < 4; ++cc)
                o_nx[cc] = orig[((size_t)(b * CC + q * 4 + cc)) * NN + nn];
        }

        // ---- partial dots over this lane's 4 channels ----
        float s[KC], d2[KC];
        float dO = 0.f;
#pragma unroll
        for (int k = 0; k < KC; ++k) { s[k] = 0.f; d2[k] = 0.f; }
#pragma unroll
        for (int cc = 0; cc < 4; ++cc) {
            dO += o[cc] * wo2[cc];
#pragma unroll
            for (int k = 0; k < KC; ++k) {
                s[k]  += v[cc][k] * ws1[cc];
                d2[k] += v[cc][k] * ws2[cc];
            }
        }

        // ---- butterfly reduce across the 4-lane point group ----
#pragma unroll
        for (int m = 1; m <= 2; m <<= 1) {
            dO += __shfl_xor(dO, m, 64);
#pragma unroll
            for (int k = 0; k < KC; ++k) {
                s[k]  += __shfl_xor(s[k],  m, 64);
                d2[k] += __shfl_xor(d2[k], m, 64);
            }
        }

        // ---- fused select (rank<4) + sigmoid + weighted sum ----
        float sum[4] = {0.f, 0.f, 0.f, 0.f};
#pragma unroll
        for (int k = 0; k < KC; ++k) {
            int rk = 0;
#pragma unroll
            for (int j = 0; j < KC; ++j) {
                if (j == k) continue;
                const bool beats = (j < k) ? (s[j] >= s[k]) : (s[j] > s[k]);
                rk += beats ? 1 : 0;
            }
            const float x  = dO + d2[k] + b2;
            const float sig = __builtin_amdgcn_rcpf(1.f + __expf(-x));
            const float wk = (rk < KT) ? sig : 0.f;
#pragma unroll
            for (int cc = 0; cc < 4; ++cc) sum[cc] += v[cc][k] * wk;
        }

        // ---- store ----
#pragma unroll
        for (int cc = 0; cc < 4; ++cc)
            out[((size_t)(b * CC + q * 4 + cc)) * NN + n] = o[cc] + sum[cc];

        // ---- retire: wait prefetch landed, publish buffer for next iter ----
        if (g + 1 < ITERS) {
            asm volatile("s_waitcnt vmcnt(0)\ns_barrier" ::: "memory");
#pragma unroll
            for (int cc = 0; cc < 4; ++cc) o[cc] = o_nx[cc];
        }
    }
}

extern "C" void kernel_launch(void* const* d_in, const int* in_sizes, int n_in,
                              void* d_out, int out_size, void* d_ws, size_t ws_size,
                              hipStream_t stream) {
    const float* orig = (const float*)d_in[0];
    const float* samp = (const float*)d_in[1];
    const float* w1   = (const float*)d_in[2];
    // d_in[3] = b1 (unused: constant shift over k does not change top-k order)
    const float* w2   = (const float*)d_in[4];
    const float* b2   = (const float*)d_in[5];
    float* out = (float*)d_out;

    const int grid = (BB * NN) / (TPTS * ITERS);   // 1024 blocks
    hipLaunchKernelGGL(swg_kernel, dim3(grid), dim3(BLK), 0, stream,
                       orig, samp, w1, w2, b2, out);
}

// Round 5
// 88.331 us; speedup vs baseline: 1.1293x; 1.1293x over previous
//
#include <hip/hip_runtime.h>
#include <math.h>

// Problem constants: B=8, C=16, N=65536, K_CAND=10, K_TOP=4
#define BB 8
#define CC 16
#define NN 65536
#define KC 10
#define KT 4

#define PTW 8              // points per wave
#define BLK 128            // 2 independent waves per block
#define PTB 16             // points per block
#define WFLT (PTW * CC * KC)   // 1280 floats = 5 KB per wave region

typedef __attribute__((address_space(3))) void lds_t;
typedef __attribute__((address_space(1))) void glob_t;

// Wave-private tiles: each wave stages its own 8-point tile via global_load_lds,
// waits vmcnt only (NO barriers at all), computes, stores, exits. 16 blocks/CU
// (LDS 10 KB) x 2 waves = 32 waves/CU = 8/SIMD; compute re-phased to fit 64 VGPR.
__global__ __launch_bounds__(BLK, 8) void swg_kernel(
    const float* __restrict__ orig,   // [B][C][N]
    const float* __restrict__ samp,   // [B][C][N][KC]
    const float* __restrict__ w1,     // [2C]
    const float* __restrict__ w2,     // [2C]
    const float* __restrict__ b2p,    // scalar
    float* __restrict__ out)          // [B][C][N]
{
    __shared__ float buf[2 * WFLT];   // 10240 B

    const int t   = threadIdx.x;
    const int l   = t & 63;
    const int w   = t >> 6;
    const int bid = blockIdx.x;

    const int b   = bid >> 12;                        // bid*16 / 65536
    const int n0w = ((bid * PTB) & (NN - 1)) + w * PTW;

    const float4* sampB4 = (const float4*)samp
        + (size_t)b * ((size_t)CC * NN * KC / 4);
    const int n0q = n0w * (KC / 2) / 2;               // n0w*10/4, exact (n0w%8==0)

    float* ldsw = buf + w * WFLT;

    // ---- stage this wave's tile: LDS linear in load order, unit m = j*64+l,
    //      global source channel c = m/20, float4-within-halfslab r = m%20 ----
#pragma unroll
    for (int j = 0; j < 5; ++j) {
        const int m = j * 64 + l;
        const int c = m / 20;
        const int r = m - c * 20;
        __builtin_amdgcn_global_load_lds(
            (const glob_t*)(sampB4 + (size_t)c * (NN * KC / 4) + n0q + r),
            (lds_t*)((char*)ldsw + j * 1024), 16, 0, 0);
    }

    const int q = l & 7;              // channel-pair id (channels q, q+8)
    const int p = l >> 3;             // local point 0..7
    const int n = n0w + p;

    float o[2];
#pragma unroll
    for (int cc = 0; cc < 2; ++cc)
        o[cc] = orig[(size_t)(b * CC + q + 8 * cc) * NN + n];

    float ws1[2], wo2[2], ws2[2];
#pragma unroll
    for (int cc = 0; cc < 2; ++cc) {
        const int c = q + 8 * cc;
        ws1[cc] = w1[CC + c];
        wo2[cc] = w2[c];
        ws2[cc] = w2[CC + c];
    }
    const float b2 = b2p[0];

    // wave-local wait for our global_load_lds (and orig) — no s_barrier
    asm volatile("s_waitcnt vmcnt(0)" ::: "memory");

    // ---- read this lane's 2 channels from LDS ----
    float v[2][KC];
#pragma unroll
    for (int cc = 0; cc < 2; ++cc) {
        const float* base = ldsw + (q + 8 * cc) * (PTW * KC) + p * KC;
#pragma unroll
        for (int j = 0; j < 5; ++j) {
            const float2 x = *(const float2*)(base + 2 * j);
            v[cc][2 * j]     = x.x;
            v[cc][2 * j + 1] = x.y;
        }
    }

    // ---- phase 1: selection scores s[k] (+ dO), butterfly over 8 lanes ----
    float s[KC];
    float dO = o[0] * wo2[0] + o[1] * wo2[1];
#pragma unroll
    for (int k = 0; k < KC; ++k)
        s[k] = v[0][k] * ws1[0] + v[1][k] * ws1[1];
#pragma unroll
    for (int m = 1; m <= 4; m <<= 1) {
        dO += __shfl_xor(dO, m, 64);
#pragma unroll
        for (int k = 0; k < KC; ++k) s[k] += __shfl_xor(s[k], m, 64);
    }

    // ---- phase 2: rank -> selection mask (s dies after this) ----
    unsigned selmask = 0;
#pragma unroll
    for (int k = 0; k < KC; ++k) {
        int rk = 0;
#pragma unroll
        for (int j = 0; j < KC; ++j) {
            if (j == k) continue;
            const bool beats = (j < k) ? (s[j] >= s[k]) : (s[j] > s[k]);
            rk += beats ? 1 : 0;
        }
        selmask |= (rk < KT) ? (1u << k) : 0u;
    }

    // ---- phase 3: recal dots d2[k], butterfly ----
    float d2[KC];
#pragma unroll
    for (int k = 0; k < KC; ++k)
        d2[k] = v[0][k] * ws2[0] + v[1][k] * ws2[1];
#pragma unroll
    for (int m = 1; m <= 4; m <<= 1) {
#pragma unroll
        for (int k = 0; k < KC; ++k) d2[k] += __shfl_xor(d2[k], m, 64);
    }

    // ---- phase 4: sigmoid weights + weighted sum + store ----
    float sum0 = 0.f, sum1 = 0.f;
#pragma unroll
    for (int k = 0; k < KC; ++k) {
        const float x   = dO + d2[k] + b2;
        const float sig = __builtin_amdgcn_rcpf(1.f + __expf(-x));
        const float wk  = ((selmask >> k) & 1u) ? sig : 0.f;
        sum0 += v[0][k] * wk;
        sum1 += v[1][k] * wk;
    }
    out[(size_t)(b * CC + q)     * NN + n] = o[0] + sum0;
    out[(size_t)(b * CC + q + 8) * NN + n] = o[1] + sum1;
}

extern "C" void kernel_launch(void* const* d_in, const int* in_sizes, int n_in,
                              void* d_out, int out_size, void* d_ws, size_t ws_size,
                              hipStream_t stream) {
    const float* orig = (const float*)d_in[0];
    const float* samp = (const float*)d_in[1];
    const float* w1   = (const float*)d_in[2];
    // d_in[3] = b1 (unused: constant shift over k does not change top-k order)
    const float* w2   = (const float*)d_in[4];
    const float* b2   = (const float*)d_in[5];
    float* out = (float*)d_out;

    const int grid = (BB * NN) / PTB;   // 32768 blocks
    hipLaunchKernelGGL(swg_kernel, dim3(grid), dim3(BLK), 0, stream,
                       orig, samp, w1, w2, b2, out);
}